// Round 7
// baseline (3486.288 us; speedup 1.0000x reference)
//
#include <hip/hip_runtime.h>
#include <stdint.h>

#define NA 200000
#define NB 200000
#define NG 10000

__device__ __forceinline__ float bf2f(unsigned short u){
  union { unsigned int i; float f; } v; v.i = ((unsigned int)u) << 16; return v.f;
}
__device__ __forceinline__ float softplus_f(float x){
  return fmaxf(x, 0.0f) + log1pf(expf(-fabsf(x)));
}
__device__ __forceinline__ float ldv(const void* p, size_t off, int isbf){
  return isbf ? bf2f(((const unsigned short*)p)[off]) : ((const float*)p)[off];
}
__device__ __forceinline__ int clampi(int v, int hi){
  return v < 0 ? 0 : (v > hi ? hi : v);
}

// ---- probes: fl[0]=feats-bf16, fl[1]=weights-bf16, fl[2]=indices-int64 ----
__global__ __launch_bounds__(64) void probe_all(
    const unsigned short* __restrict__ af, const unsigned short* __restrict__ w,
    const int* __restrict__ amol, int* __restrict__ fl)
{
  int l = threadIdx.x;
  unsigned short ua = af[2 * l], uw = w[2 * l];
  int ea = (ua >> 7) & 0xFF, ew = (uw >> 7) & 0xFF;
  unsigned long long ma = __ballot(ea >= 0x70 && ea <= 0x8F);
  unsigned long long mw = __ballot(ew >= 0x70 && ew <= 0x8F);
  unsigned long long mi = __ballot(amol[2 * l + 1] == 0);
  if (l == 0) {
    fl[0] = (__popcll(ma) >= 32) ? 1 : 0;
    fl[1] = (__popcll(mw) >= 32) ? 1 : 0;
    fl[2] = (__popcll(mi) == 64) ? 1 : 0;
  }
}

__global__ void sentinel(float* outf, float code){ outf[0] = code; }

// ---- bond->atom edge sum (f32 atomics), dst-range filtered ----
__global__ __launch_bounds__(256) void edge_sum(
    const void* __restrict__ bond, const int* __restrict__ ba,
    float* __restrict__ sums, float* __restrict__ cnt,
    int lo, int hi, const int* __restrict__ fl)
{
  const int featbf = fl[0];
  const int istr = 1 + fl[2];
  int col  = threadIdx.x & 127;
  int half = threadIdx.x >> 7;
  for (long e = (long)blockIdx.x * 2 + half; e < 2L * NB; e += (long)gridDim.x * 2) {
    int dst = ba[(size_t)e * istr];
    if (dst < lo || dst >= hi) continue;        // drop OOB (segment_sum semantics)
    long brow = e >> 1;
    float v = featbf ? bf2f(((const unsigned short*)bond)[brow * 128 + col])
                     : ((const float*)bond)[brow * 128 + col];
    atomicAdd(sums + (size_t)(dst - lo) * 128 + col, v);
    if (col == 0) atomicAdd(cnt + (dst - lo), 1.0f);
  }
}

// ---- atom MLP (f32), fused global-mean scatter ----
__global__ __launch_bounds__(128) void atom_mlp(
    const void* __restrict__ af, const void* __restrict__ gfv,
    const float* __restrict__ sums, const float* __restrict__ cnt,
    const int* __restrict__ amol,
    const void* __restrict__ w0, const void* __restrict__ b0,
    const void* __restrict__ w1, const void* __restrict__ b1,
    const void* __restrict__ w2, const void* __restrict__ b2,
    float* __restrict__ outA, float* __restrict__ gsA, float* __restrict__ gcA,
    int lo, int hi, const int* __restrict__ fl)
{
  __shared__ float cat[16][384];
  __shared__ float hid[16][128];
  const int t = threadIdx.x;
  const int row0 = lo + blockIdx.x * 16;
  const int featbf = fl[0], wbf = fl[1], istr = 1 + fl[2];

  for (int r = 0; r < 16; r++) {
    int row = row0 + r;
    if (row >= hi) { cat[r][t]=0.f; cat[r][128+t]=0.f; cat[r][256+t]=0.f; continue; }
    cat[r][t] = ldv(af, (size_t)row * 128 + t, featbf);
    float cv = cnt[row - lo];
    cat[r][128 + t] = cv > 0.f ? sums[(size_t)(row - lo) * 128 + t] / cv : 0.f;
    int g = clampi(amol[(size_t)row * istr], NG - 1);
    cat[r][256 + t] = ldv(gfv, (size_t)g * 128 + t, featbf);
  }
  __syncthreads();

  float acc[16];
  { float bb = ldv(b0, t, wbf);
    for (int r = 0; r < 16; r++) acc[r] = bb;
    #pragma unroll 4
    for (int k = 0; k < 384; k++) {
      float wv = ldv(w0, (size_t)k * 128 + t, wbf);
      for (int r = 0; r < 16; r++) acc[r] = fmaf(cat[r][k], wv, acc[r]);
    } }
  __syncthreads();
  for (int r = 0; r < 16; r++) hid[r][t] = softplus_f(acc[r]);
  __syncthreads();
  { float bb = ldv(b1, t, wbf);
    for (int r = 0; r < 16; r++) acc[r] = bb;
    #pragma unroll 4
    for (int k = 0; k < 128; k++) {
      float wv = ldv(w1, (size_t)k * 128 + t, wbf);
      for (int r = 0; r < 16; r++) acc[r] = fmaf(hid[r][k], wv, acc[r]);
    } }
  __syncthreads();
  for (int r = 0; r < 16; r++) hid[r][t] = softplus_f(acc[r]);
  __syncthreads();
  { float bb = ldv(b2, t, wbf);
    for (int r = 0; r < 16; r++) acc[r] = bb;
    #pragma unroll 4
    for (int k = 0; k < 128; k++) {
      float wv = ldv(w2, (size_t)k * 128 + t, wbf);
      for (int r = 0; r < 16; r++) acc[r] = fmaf(hid[r][k], wv, acc[r]);
    } }
  for (int r = 0; r < 16; r++) {
    int row = row0 + r;
    if (row >= hi) break;
    float v = acc[r];
    outA[(size_t)row * 128 + t] = v;
    int g = amol[(size_t)row * istr];
    if (g >= 0 && g < NG) {                     // drop (scatter semantics)
      atomicAdd(gsA + (size_t)g * 128 + t, v);
      if (t == 0) atomicAdd(gcA + g, 1.0f);
    }
  }
}

// ---- bond MLP (f32), gathers f32 atom_out from d_out, fused scatter ----
__global__ __launch_bounds__(128) void bond_mlp(
    const void* __restrict__ bf_, const void* __restrict__ gfv,
    const int* __restrict__ ba, const int* __restrict__ bmol,
    const float* __restrict__ outA,
    const void* __restrict__ w0, const void* __restrict__ b0,
    const void* __restrict__ w1, const void* __restrict__ b1,
    const void* __restrict__ w2, const void* __restrict__ b2,
    float* __restrict__ outB, float* __restrict__ gsB, float* __restrict__ gcB,
    const int* __restrict__ fl)
{
  __shared__ float cat[16][512];
  __shared__ float hid[16][128];
  const int t = threadIdx.x;
  const int row0 = blockIdx.x * 16;
  const int featbf = fl[0], wbf = fl[1], istr = 1 + fl[2];

  for (int r = 0; r < 16; r++) {
    int row = row0 + r;
    if (row >= NB) { cat[r][t]=0.f; cat[r][128+t]=0.f; cat[r][256+t]=0.f; cat[r][384+t]=0.f; continue; }
    cat[r][t] = ldv(bf_, (size_t)row * 128 + t, featbf);
    int a0 = clampi(ba[(size_t)(row * 2 + 0) * istr], NA - 1);
    int a1 = clampi(ba[(size_t)(row * 2 + 1) * istr], NA - 1);
    cat[r][128 + t] = outA[(size_t)a0 * 128 + t];
    cat[r][256 + t] = outA[(size_t)a1 * 128 + t];
    int g = clampi(bmol[(size_t)row * istr], NG - 1);
    cat[r][384 + t] = ldv(gfv, (size_t)g * 128 + t, featbf);
  }
  __syncthreads();

  float acc[16];
  { float bb = ldv(b0, t, wbf);
    for (int r = 0; r < 16; r++) acc[r] = bb;
    #pragma unroll 4
    for (int k = 0; k < 512; k++) {
      float wv = ldv(w0, (size_t)k * 128 + t, wbf);
      for (int r = 0; r < 16; r++) acc[r] = fmaf(cat[r][k], wv, acc[r]);
    } }
  __syncthreads();
  for (int r = 0; r < 16; r++) hid[r][t] = softplus_f(acc[r]);
  __syncthreads();
  { float bb = ldv(b1, t, wbf);
    for (int r = 0; r < 16; r++) acc[r] = bb;
    #pragma unroll 4
    for (int k = 0; k < 128; k++) {
      float wv = ldv(w1, (size_t)k * 128 + t, wbf);
      for (int r = 0; r < 16; r++) acc[r] = fmaf(hid[r][k], wv, acc[r]);
    } }
  __syncthreads();
  for (int r = 0; r < 16; r++) hid[r][t] = softplus_f(acc[r]);
  __syncthreads();
  { float bb = ldv(b2, t, wbf);
    for (int r = 0; r < 16; r++) acc[r] = bb;
    #pragma unroll 4
    for (int k = 0; k < 128; k++) {
      float wv = ldv(w2, (size_t)k * 128 + t, wbf);
      for (int r = 0; r < 16; r++) acc[r] = fmaf(hid[r][k], wv, acc[r]);
    } }
  for (int r = 0; r < 16; r++) {
    int row = row0 + r;
    if (row >= NB) break;
    float v = acc[r];
    outB[(size_t)row * 128 + t] = v;
    int g = bmol[(size_t)row * istr];
    if (g >= 0 && g < NG) {
      atomicAdd(gsB + (size_t)g * 128 + t, v);
      if (t == 0) atomicAdd(gcB + g, 1.0f);
    }
  }
}

// ---- global MLP (f32) ----
__global__ __launch_bounds__(128) void glob_mlp(
    const void* __restrict__ gfv,
    const float* __restrict__ gsA, const float* __restrict__ gcA,
    const float* __restrict__ gsB, const float* __restrict__ gcB,
    const void* __restrict__ w0, const void* __restrict__ b0,
    const void* __restrict__ w1, const void* __restrict__ b1,
    const void* __restrict__ w2, const void* __restrict__ b2,
    float* __restrict__ outG, const int* __restrict__ fl)
{
  __shared__ float cat[16][384];
  __shared__ float hid[16][128];
  const int t = threadIdx.x;
  const int row0 = blockIdx.x * 16;
  const int featbf = fl[0], wbf = fl[1];

  for (int r = 0; r < 16; r++) {
    int row = row0 + r;
    if (row >= NG) { cat[r][t]=0.f; cat[r][128+t]=0.f; cat[r][256+t]=0.f; continue; }
    cat[r][t] = ldv(gfv, (size_t)row * 128 + t, featbf);
    float ca = gcA[row], cb = gcB[row];
    cat[r][128 + t] = ca > 0.f ? gsA[(size_t)row * 128 + t] / ca : 0.f;
    cat[r][256 + t] = cb > 0.f ? gsB[(size_t)row * 128 + t] / cb : 0.f;
  }
  __syncthreads();

  float acc[16];
  { float bb = ldv(b0, t, wbf);
    for (int r = 0; r < 16; r++) acc[r] = bb;
    #pragma unroll 4
    for (int k = 0; k < 384; k++) {
      float wv = ldv(w0, (size_t)k * 128 + t, wbf);
      for (int r = 0; r < 16; r++) acc[r] = fmaf(cat[r][k], wv, acc[r]);
    } }
  __syncthreads();
  for (int r = 0; r < 16; r++) hid[r][t] = softplus_f(acc[r]);
  __syncthreads();
  { float bb = ldv(b1, t, wbf);
    for (int r = 0; r < 16; r++) acc[r] = bb;
    #pragma unroll 4
    for (int k = 0; k < 128; k++) {
      float wv = ldv(w1, (size_t)k * 128 + t, wbf);
      for (int r = 0; r < 16; r++) acc[r] = fmaf(hid[r][k], wv, acc[r]);
    } }
  __syncthreads();
  for (int r = 0; r < 16; r++) hid[r][t] = softplus_f(acc[r]);
  __syncthreads();
  { float bb = ldv(b2, t, wbf);
    for (int r = 0; r < 16; r++) acc[r] = bb;
    #pragma unroll 4
    for (int k = 0; k < 128; k++) {
      float wv = ldv(w2, (size_t)k * 128 + t, wbf);
      for (int r = 0; r < 16; r++) acc[r] = fmaf(hid[r][k], wv, acc[r]);
    } }
  for (int r = 0; r < 16; r++) {
    int row = row0 + r;
    if (row >= NG) break;
    outG[(size_t)row * 128 + t] = acc[r];
  }
}

extern "C" void kernel_launch(void* const* d_in, const int* in_sizes, int n_in,
                              void* d_out, int out_size, void* d_ws, size_t ws_size,
                              hipStream_t stream)
{
  const void* atomF = d_in[0];
  const void* bondF = d_in[1];
  const void* globF = d_in[2];
  const int* bondAtom = (const int*)d_in[3];
  const int* atomMol  = (const int*)d_in[4];
  const int* bondMol  = (const int*)d_in[5];
  const void* W[18];
  for (int i = 0; i < 18; i++) W[i] = d_in[6 + i];

  float* outAtom = (float*)d_out;              // d_out is FLOAT32 (proven R6)
  float* outBond = outAtom + (size_t)NA * 128;
  float* outGlob = outBond + (size_t)NB * 128;

  // ---- contract validation ----
  const int expect[24] = {
    NA*128, NB*128, NG*128, NB*2, NA, NB,
    384*128, 128, 128*128, 128, 128*128, 128,
    512*128, 128, 128*128, 128, 128*128, 128,
    384*128, 128, 128*128, 128, 128*128, 128 };
  if (n_in != 24) { sentinel<<<1,1,0,stream>>>(outAtom, 8192.0f); return; }
  for (int i = 0; i < 24; i++)
    if (in_sizes[i] != expect[i]) {
      sentinel<<<1,1,0,stream>>>(outAtom, 16384.0f + 256.0f * (float)i);
      return;
    }
  if (out_size != (NA + NB + NG) * 128) {
    sentinel<<<1,1,0,stream>>>(outAtom, 1024.0f); return;
  }

  // ---- ws layout: flags | gsA gcA gsB gcB (10.32MB) | chunked edge sums ----
  char* ws = (char*)d_ws;
  int* fl = (int*)ws;                                  // 256 B
  const size_t gsOff = 256;
  float* gsA = (float*)(ws + gsOff);
  float* gcA = (float*)(ws + gsOff + 5120000);
  float* gsB = (float*)(ws + gsOff + 5160000);
  float* gcB = (float*)(ws + gsOff + 10280000);
  const size_t chOff = gsOff + 10320000;
  size_t avail = ws_size > chOff ? ws_size - chOff : 0;
  long chunkRows = (long)(avail / 516) & ~15L;
  if (chunkRows < 16) chunkRows = 16;
  if (chunkRows > NA) chunkRows = NA;
  float* sums = (float*)(ws + chOff);
  float* cnt  = (float*)(ws + chOff + (size_t)chunkRows * 512);

  probe_all<<<1, 64, 0, stream>>>((const unsigned short*)atomF,
                                  (const unsigned short*)W[0], atomMol, fl);
  hipMemsetAsync(ws + gsOff, 0, 10320000, stream);

  // ---- stage 1: atoms (chunked edge-mean + MLP, fused gsA scatter) ----
  for (long lo = 0; lo < NA; lo += chunkRows) {
    long hi = lo + chunkRows; if (hi > NA) hi = NA;
    int rows = (int)(hi - lo);
    hipMemsetAsync(ws + chOff, 0, (size_t)chunkRows * 516, stream);
    edge_sum<<<2048, 256, 0, stream>>>(bondF, bondAtom, sums, cnt,
                                       (int)lo, (int)hi, fl);
    atom_mlp<<<(rows + 15) / 16, 128, 0, stream>>>(
        atomF, globF, sums, cnt, atomMol,
        W[0], W[1], W[2], W[3], W[4], W[5],
        outAtom, gsA, gcA, (int)lo, (int)hi, fl);
  }

  // ---- stage 2: bonds (fused gsB scatter) ----
  bond_mlp<<<(NB + 15) / 16, 128, 0, stream>>>(
      bondF, globF, bondAtom, bondMol, outAtom,
      W[6], W[7], W[8], W[9], W[10], W[11],
      outBond, gsB, gcB, fl);

  // ---- stage 3: globals ----
  glob_mlp<<<(NG + 15) / 16, 128, 0, stream>>>(
      globF, gsA, gcA, gsB, gcB,
      W[12], W[13], W[14], W[15], W[16], W[17],
      outGlob, fl);
}

// Round 8
// 1010.904 us; speedup vs baseline: 3.4487x; 3.4487x over previous
//
#include <hip/hip_runtime.h>
#include <stdint.h>

#define NA 200000
#define NB 200000
#define NG 10000

typedef short bf16x8 __attribute__((ext_vector_type(8)));
typedef float f32x4 __attribute__((ext_vector_type(4)));

__device__ __forceinline__ float bf2f(unsigned short u){
  union { unsigned int i; float f; } v; v.i = ((unsigned int)u) << 16; return v.f;
}
__device__ __forceinline__ unsigned short f2bf(float f){
  union { float f; unsigned int i; } v; v.f = f;
  unsigned int x = v.i;
  unsigned int r = (x + 0x7FFFu + ((x >> 16) & 1u)) >> 16;
  if ((x & 0x7F800000u) == 0x7F800000u) r = x >> 16;
  return (unsigned short)r;
}
__device__ __forceinline__ float softplus_f(float x){
  return fmaxf(x, 0.0f) + log1pf(expf(-fabsf(x)));
}
__device__ __forceinline__ float ldv(const void* p, size_t off, int isbf){
  return isbf ? bf2f(((const unsigned short*)p)[off]) : ((const float*)p)[off];
}
__device__ __forceinline__ int clampi(int v, int hi){
  return v < 0 ? 0 : (v > hi ? hi : v);
}

// ---- probes: fl[0]=feats-bf16, fl[1]=weights-bf16, fl[2]=indices-int64 ----
__global__ __launch_bounds__(64) void probe_all(
    const unsigned short* __restrict__ af, const unsigned short* __restrict__ w,
    const int* __restrict__ amol, int* __restrict__ fl)
{
  int l = threadIdx.x;
  unsigned short ua = af[2 * l], uw = w[2 * l];
  int ea = (ua >> 7) & 0xFF, ew = (uw >> 7) & 0xFF;
  unsigned long long ma = __ballot(ea >= 0x70 && ea <= 0x8F);
  unsigned long long mw = __ballot(ew >= 0x70 && ew <= 0x8F);
  unsigned long long mi = __ballot(amol[2 * l + 1] == 0);
  if (l == 0) {
    fl[0] = (__popcll(ma) >= 32) ? 1 : 0;
    fl[1] = (__popcll(mw) >= 32) ? 1 : 0;
    fl[2] = (__popcll(mi) == 64) ? 1 : 0;
  }
}

__global__ void sentinel(float* outf, float code){ outf[0] = code; }

// ---- bond->atom edge sum (f32 atomics), dst-range filtered ----
__global__ __launch_bounds__(256) void edge_sum(
    const void* __restrict__ bond, const int* __restrict__ ba,
    float* __restrict__ sums, float* __restrict__ cnt,
    int lo, int hi, const int* __restrict__ fl)
{
  const int featbf = fl[0];
  const int istr = 1 + fl[2];
  int col  = threadIdx.x & 127;
  int half = threadIdx.x >> 7;
  for (long e = (long)blockIdx.x * 2 + half; e < 2L * NB; e += (long)gridDim.x * 2) {
    int dst = ba[(size_t)e * istr];
    if (dst < lo || dst >= hi) continue;
    long brow = e >> 1;
    float v = featbf ? bf2f(((const unsigned short*)bond)[brow * 128 + col])
                     : ((const float*)bond)[brow * 128 + col];
    atomicAdd(sums + (size_t)(dst - lo) * 128 + col, v);
    if (col == 0) atomicAdd(cnt + (dst - lo), 1.0f);
  }
}

// ---- repack weights [K][128] -> MFMA B-fragment-major bf16 ----
// frag (kt,nb): element(lane,i) = w[kt*32 + (lane>>4)*8 + i][nb*16 + (lane&15)]
__global__ __launch_bounds__(64) void repack_w(
    const void* __restrict__ w, unsigned short* __restrict__ dst,
    const int* __restrict__ fl)
{
  int wbf = fl[1];
  int f = blockIdx.x; int kt = f >> 3; int nb = f & 7; int l = threadIdx.x;
  alignas(16) unsigned short t[8];
  #pragma unroll
  for (int i = 0; i < 8; i++) {
    size_t off = (size_t)(kt * 32 + ((l >> 4) << 3) + i) * 128 + nb * 16 + (l & 15);
    t[i] = f2bf(ldv(w, off, wbf));
  }
  *(uint4*)(dst + (size_t)f * 512 + l * 8) = *(const uint4*)t;
}

// ---- one layer on a 32-row tile; wave handles col-blocks {2w, 2w+1} ----
template<int KT, bool FINAL>
__device__ __forceinline__ void run_layer32(
    const char* inbuf, int rowbIn,
    const unsigned short* __restrict__ wpL, const void* __restrict__ biasL, int wbf,
    char* outbuf,
    float* __restrict__ outSec, float* __restrict__ gs, float* __restrict__ gc,
    const int* __restrict__ idxS, int istr, int row0, int rowHi,
    int lane, int wave)
{
  const int nb0 = wave * 2;
  const int colA = lane & 15;
  const int swz = (lane & 7) << 4;
  const int kb = (lane >> 4) << 4;   // byte offset of lane-group's 8 bf16 in k
  float bb0 = ldv(biasL, nb0 * 16 + colA, wbf);
  float bb1 = ldv(biasL, nb0 * 16 + 16 + colA, wbf);
  f32x4 acc[2][2];
  #pragma unroll
  for (int s = 0; s < 2; s++) {
    acc[s][0] = f32x4{bb0, bb0, bb0, bb0};
    acc[s][1] = f32x4{bb1, bb1, bb1, bb1};
  }
  #pragma unroll
  for (int kt = 0; kt < KT; ++kt) {
    bf16x8 b0 = *(const bf16x8*)(wpL + ((size_t)(kt * 8 + nb0) << 9) + lane * 8);
    bf16x8 b1 = *(const bf16x8*)(wpL + ((size_t)(kt * 8 + nb0 + 1) << 9) + lane * 8);
    #pragma unroll
    for (int s = 0; s < 2; s++) {
      bf16x8 a = *(const bf16x8*)(inbuf + (s * 16 + colA) * rowbIn + ((kt * 64 + kb) ^ swz));
      acc[s][0] = __builtin_amdgcn_mfma_f32_16x16x32_bf16(a, b0, acc[s][0], 0, 0, 0);
      acc[s][1] = __builtin_amdgcn_mfma_f32_16x16x32_bf16(a, b1, acc[s][1], 0, 0, 0);
    }
  }
  #pragma unroll
  for (int s = 0; s < 2; s++)
    #pragma unroll
    for (int j = 0; j < 2; j++)
      #pragma unroll
      for (int rr = 0; rr < 4; rr++) {
        int row = s * 16 + ((lane >> 4) << 2) + rr;
        int col = (nb0 + j) * 16 + colA;
        float v = acc[s][j][rr];
        if (!FINAL) {
          v = softplus_f(v);
          *(unsigned short*)(outbuf + row * 256 + ((col * 2) ^ ((row & 7) << 4))) = f2bf(v);
        } else {
          int grow = row0 + row;
          if (grow < rowHi) {
            outSec[(size_t)grow * 128 + col] = v;
            if (gs) {
              int g = idxS[(size_t)grow * istr];
              if (g >= 0 && g < NG) {
                atomicAdd(gs + (size_t)g * 128 + col, v);
                if (wave == 0 && colA == 0 && j == 0) atomicAdd(gc + g, 1.0f);
              }
            }
          }
        }
      }
}

// ---- fused 3-layer MFMA MLP over 32-row tiles ----
// MODE 0: atom  cat=[atom | mean_bond | glob[amol]]   KIN=384, scatter gsA by amol
// MODE 1: bond  cat=[bond | A[ba0] | A[ba1] | glob]   KIN=512, scatter gsB by bmol
// MODE 2: glob  cat=[glob | meanA | meanB]            KIN=384, no scatter
template<int KIN, int MODE>
__global__ __launch_bounds__(256) void mfma_mlp(
    const void* __restrict__ x0,
    const float* __restrict__ s1, const float* __restrict__ c1,
    const float* __restrict__ s2, const float* __restrict__ c2,
    const void* __restrict__ gfv,
    const int* __restrict__ idxA, const int* __restrict__ idxS,
    const float* __restrict__ gatherA,
    const unsigned short* __restrict__ wp0, const unsigned short* __restrict__ wp1,
    const unsigned short* __restrict__ wp2,
    const void* __restrict__ b0, const void* __restrict__ b1,
    const void* __restrict__ b2,
    float* __restrict__ outSec, float* __restrict__ gs, float* __restrict__ gc,
    int rowLo, int rowHi, const int* __restrict__ fl)
{
  constexpr int ROWB = KIN * 2;
  constexpr int CPR  = KIN / 8;      // 16B chunks per row
  __shared__ char sm[32 * ROWB + 16384];
  char* act0 = sm + 32 * ROWB;
  char* act1 = act0 + 8192;
  const int tid = threadIdx.x;
  const int row0 = rowLo + blockIdx.x * 32;
  const int featbf = fl[0], wbf = fl[1], istr = 1 + fl[2];

  // ---- stage concatenated input tile as swizzled bf16 ----
  for (int ch = tid; ch < 32 * CPR; ch += 256) {
    int r = ch / CPR, c8 = ch % CPR;
    int row = row0 + r;
    int seg = c8 * 8;
    alignas(16) unsigned short h[8];
    if (row >= rowHi) {
      #pragma unroll
      for (int j = 0; j < 8; j++) h[j] = 0;
    } else {
      float v[8];
      if constexpr (MODE == 0) {
        if (seg < 128) {
          #pragma unroll
          for (int j = 0; j < 8; j++) v[j] = ldv(x0, (size_t)row * 128 + seg + j, featbf);
        } else if (seg < 256) {
          float cv = c1[row - rowLo]; float inv = cv > 0.f ? 1.f / cv : 0.f;
          #pragma unroll
          for (int j = 0; j < 8; j++) v[j] = s1[(size_t)(row - rowLo) * 128 + seg - 128 + j] * inv;
        } else {
          int g = clampi(idxA[(size_t)row * istr], NG - 1);
          #pragma unroll
          for (int j = 0; j < 8; j++) v[j] = ldv(gfv, (size_t)g * 128 + seg - 256 + j, featbf);
        }
      } else if constexpr (MODE == 1) {
        if (seg < 128) {
          #pragma unroll
          for (int j = 0; j < 8; j++) v[j] = ldv(x0, (size_t)row * 128 + seg + j, featbf);
        } else if (seg < 384) {
          int q = (seg < 256) ? 0 : 1;
          int a = clampi(idxA[(size_t)(row * 2 + q) * istr], NA - 1);
          int sc = seg - 128 - q * 128;
          #pragma unroll
          for (int j = 0; j < 8; j++) v[j] = gatherA[(size_t)a * 128 + sc + j];
        } else {
          int g = clampi(idxS[(size_t)row * istr], NG - 1);
          #pragma unroll
          for (int j = 0; j < 8; j++) v[j] = ldv(gfv, (size_t)g * 128 + seg - 384 + j, featbf);
        }
      } else {
        if (seg < 128) {
          #pragma unroll
          for (int j = 0; j < 8; j++) v[j] = ldv(x0, (size_t)row * 128 + seg + j, featbf);
        } else if (seg < 256) {
          float cv = c1[row]; float inv = cv > 0.f ? 1.f / cv : 0.f;
          #pragma unroll
          for (int j = 0; j < 8; j++) v[j] = s1[(size_t)row * 128 + seg - 128 + j] * inv;
        } else {
          float cv = c2[row]; float inv = cv > 0.f ? 1.f / cv : 0.f;
          #pragma unroll
          for (int j = 0; j < 8; j++) v[j] = s2[(size_t)row * 128 + seg - 256 + j] * inv;
        }
      }
      #pragma unroll
      for (int j = 0; j < 8; j++) h[j] = f2bf(v[j]);
    }
    *(uint4*)(sm + r * ROWB + ((c8 * 16) ^ ((r & 7) << 4))) = *(const uint4*)h;
  }
  __syncthreads();

  const int lane = tid & 63, wave = tid >> 6;
  run_layer32<KIN / 32, false>(sm, ROWB, wp0, b0, wbf, act0,
                               nullptr, nullptr, nullptr, nullptr, 1, 0, 0, lane, wave);
  __syncthreads();
  run_layer32<4, false>(act0, 256, wp1, b1, wbf, act1,
                        nullptr, nullptr, nullptr, nullptr, 1, 0, 0, lane, wave);
  __syncthreads();
  run_layer32<4, true>(act1, 256, wp2, b2, wbf, nullptr,
                       outSec, gs, gc, idxS, istr, row0, rowHi, lane, wave);
}

extern "C" void kernel_launch(void* const* d_in, const int* in_sizes, int n_in,
                              void* d_out, int out_size, void* d_ws, size_t ws_size,
                              hipStream_t stream)
{
  const void* atomF = d_in[0];
  const void* bondF = d_in[1];
  const void* globF = d_in[2];
  const int* bondAtom = (const int*)d_in[3];
  const int* atomMol  = (const int*)d_in[4];
  const int* bondMol  = (const int*)d_in[5];
  const void* W[18];
  for (int i = 0; i < 18; i++) W[i] = d_in[6 + i];

  float* outAtom = (float*)d_out;              // f32 (proven R6/R7)
  float* outBond = outAtom + (size_t)NA * 128;
  float* outGlob = outBond + (size_t)NB * 128;

  // ---- contract validation ----
  const int expect[24] = {
    NA*128, NB*128, NG*128, NB*2, NA, NB,
    384*128, 128, 128*128, 128, 128*128, 128,
    512*128, 128, 128*128, 128, 128*128, 128,
    384*128, 128, 128*128, 128, 128*128, 128 };
  if (n_in != 24) { sentinel<<<1,1,0,stream>>>(outAtom, 8192.0f); return; }
  for (int i = 0; i < 24; i++)
    if (in_sizes[i] != expect[i]) {
      sentinel<<<1,1,0,stream>>>(outAtom, 16384.0f + 256.0f * (float)i);
      return;
    }
  if (out_size != (NA + NB + NG) * 128) {
    sentinel<<<1,1,0,stream>>>(outAtom, 1024.0f); return;
  }

  // ---- ws layout: fl | packed weights 512KB | gs 10.32MB | chunk scratch ----
  char* ws = (char*)d_ws;
  int* fl = (int*)ws;                                   // 256 B
  unsigned short* wp = (unsigned short*)(ws + 256);     // 512 KiB
  const size_t gsOff = 256 + 524288;
  float* gsA = (float*)(ws + gsOff);
  float* gcA = (float*)(ws + gsOff + 5120000);
  float* gsB = (float*)(ws + gsOff + 5160000);
  float* gcB = (float*)(ws + gsOff + 10280000);
  const size_t chOff = gsOff + 10320000;
  size_t avail = ws_size > chOff ? ws_size - chOff : 0;
  long chunkRows = (long)(avail / 516) & ~31L;
  if (chunkRows < 32) chunkRows = 32;
  if (chunkRows > NA) chunkRows = NA;
  float* sums = (float*)(ws + chOff);
  float* cnt  = (float*)(ws + chOff + (size_t)chunkRows * 512);

  probe_all<<<1, 64, 0, stream>>>((const unsigned short*)atomF,
                                  (const unsigned short*)W[0], atomMol, fl);
  hipMemsetAsync(ws + gsOff, 0, 10320000, stream);

  // ---- weight repack (fragment-major bf16); offsets in ushorts ----
  repack_w<<<96, 64, 0, stream>>>(W[0],  wp + 0,      fl);
  repack_w<<<32, 64, 0, stream>>>(W[2],  wp + 49152,  fl);
  repack_w<<<32, 64, 0, stream>>>(W[4],  wp + 65536,  fl);
  repack_w<<<128,64, 0, stream>>>(W[6],  wp + 81920,  fl);
  repack_w<<<32, 64, 0, stream>>>(W[8],  wp + 147456, fl);
  repack_w<<<32, 64, 0, stream>>>(W[10], wp + 163840, fl);
  repack_w<<<96, 64, 0, stream>>>(W[12], wp + 180224, fl);
  repack_w<<<32, 64, 0, stream>>>(W[14], wp + 229376, fl);
  repack_w<<<32, 64, 0, stream>>>(W[16], wp + 245760, fl);

  // ---- stage 1: atoms (chunked edge-mean + MFMA MLP, fused gsA scatter) ----
  for (long lo = 0; lo < NA; lo += chunkRows) {
    long hi = lo + chunkRows; if (hi > NA) hi = NA;
    int rows = (int)(hi - lo);
    hipMemsetAsync(ws + chOff, 0, (size_t)chunkRows * 516, stream);
    edge_sum<<<2048, 256, 0, stream>>>(bondF, bondAtom, sums, cnt,
                                       (int)lo, (int)hi, fl);
    mfma_mlp<384, 0><<<(rows + 31) / 32, 256, 0, stream>>>(
        atomF, sums, cnt, nullptr, nullptr, globF, atomMol, atomMol, nullptr,
        wp + 0, wp + 49152, wp + 65536, W[1], W[3], W[5],
        outAtom, gsA, gcA, (int)lo, (int)hi, fl);
  }

  // ---- stage 2: bonds (gathers f32 atom_out, fused gsB scatter) ----
  mfma_mlp<512, 1><<<(NB + 31) / 32, 256, 0, stream>>>(
      bondF, nullptr, nullptr, nullptr, nullptr, globF, bondAtom, bondMol, outAtom,
      wp + 81920, wp + 147456, wp + 163840, W[7], W[9], W[11],
      outBond, gsB, gcB, 0, NB, fl);

  // ---- stage 3: globals ----
  mfma_mlp<384, 2><<<(NG + 31) / 32, 256, 0, stream>>>(
      globF, gsA, gcA, gsB, gcB, nullptr, nullptr, nullptr, nullptr,
      wp + 180224, wp + 229376, wp + 245760, W[13], W[15], W[17],
      outGlob, nullptr, nullptr, 0, NG, fl);
}